// Round 8
// baseline (224.281 us; speedup 1.0000x reference)
//
#include <hip/hip_runtime.h>

typedef unsigned short u16;
typedef unsigned int u32;

typedef __attribute__((ext_vector_type(8))) short bf16x8;
typedef __attribute__((ext_vector_type(4))) float f32x4;

#define CAP 20480      // staging capacity per bucket (mean ~16384 at E=800k, +32 sigma)
#define OVFCAP 4096
#define CHUNK 4096     // edges per binA block

__device__ __forceinline__ float bf2f(u16 u) {
    return __uint_as_float(((u32)u) << 16);
}
__device__ __forceinline__ u16 f2bf(float f) {
    u32 x = __float_as_uint(f);
    return (u16)((x + 0x7fffu + ((x >> 16) & 1u)) >> 16);
}

// block-uniform dtype flag: true if x is bf16, false if fp32.
__device__ __forceinline__ bool block_isbf(const u16* __restrict__ x, float* sflag) {
    int tid = threadIdx.x;
    if (tid < 64) {
        u16 v = x[tid * 2];
        u32 ex = (v >> 7) & 0xFFu;
        unsigned long long m = __ballot(ex >= 90u && ex <= 140u);
        if (tid == 0) *sflag = (m == ~0ull) ? 1.0f : 0.0f;
    }
    __syncthreads();
    return *sflag != 0.0f;
}

// 32-lane-group gather accumulate: ax,ay += feats of rows csr[s0..s1) at u32-col `lane`.
__device__ __forceinline__ void gather_accum(
    const u32* __restrict__ fl, const u16* __restrict__ csr,
    int s0, int s1, int lane, float& ax, float& ay) {
    int deg = s1 - s0;
    for (int base = 0; base < deg; base += 32) {
        int m = min(deg - base, 32);
        int idx = 0;
        if (lane < m) idx = (int)csr[s0 + base + lane];
        int j = 0;
        for (; j + 8 <= m; j += 8) {
            u32 wv[8];
#pragma unroll
            for (int u = 0; u < 8; u++) {
                int sv = __shfl(idx, j + u, 32);
                wv[u] = fl[(size_t)sv * 32];
            }
#pragma unroll
            for (int u = 0; u < 8; u++) {
                ax += bf2f((u16)(wv[u] & 0xFFFFu));
                ay += bf2f((u16)(wv[u] >> 16));
            }
        }
        for (; j + 4 <= m; j += 4) {
            u32 wv[4];
#pragma unroll
            for (int u = 0; u < 4; u++) {
                int sv = __shfl(idx, j + u, 32);
                wv[u] = fl[(size_t)sv * 32];
            }
#pragma unroll
            for (int u = 0; u < 4; u++) {
                ax += bf2f((u16)(wv[u] & 0xFFFFu));
                ay += bf2f((u16)(wv[u] >> 16));
            }
        }
        for (; j < m; j++) {
            int sv = __shfl(idx, j, 32);
            u32 wa = fl[(size_t)sv * 32];
            ax += bf2f((u16)(wa & 0xFFFFu));
            ay += bf2f((u16)(wa >> 16));
        }
    }
}

// Phase A: per-node degree count + bucket-binning of edges into staging.
// bucket(d) = d >> 10 (1024 nodes per bucket). Packed entry: src | (d&1023)<<16.
__global__ __launch_bounds__(256) void k_binA(
    const int* __restrict__ src, const int* __restrict__ dst,
    int* __restrict__ cnt, int* __restrict__ gcur,
    u32* __restrict__ staging, u32* __restrict__ ovf, int* __restrict__ ovfcur,
    int E) {
    __shared__ int hcnt[64];
    __shared__ int hbase[64];
    const int tid = threadIdx.x;
    const int e0 = blockIdx.x * CHUNK;
    const int e1 = min(e0 + CHUNK, E);
    if (tid < 64) hcnt[tid] = 0;
    __syncthreads();
    for (int e = e0 + tid; e < e1; e += 256) {
        int d = dst[e];
        atomicAdd(&cnt[d], 1);          // per-node in-degree (global)
        atomicAdd(&hcnt[d >> 10], 1);   // LDS bucket histogram
    }
    __syncthreads();
    if (tid < 64) {
        int c = hcnt[tid];
        hbase[tid] = (c > 0) ? atomicAdd(&gcur[tid], c) : 0;
        hcnt[tid] = 0;                   // reuse as local cursor
    }
    __syncthreads();
    for (int e = e0 + tid; e < e1; e += 256) {
        int d = dst[e];
        int s = src[e];
        int b = d >> 10;
        int r = atomicAdd(&hcnt[b], 1);  // LDS rank
        int p = hbase[b] + r;
        if (p < CAP) {
            staging[(size_t)b * CAP + p] = (u32)s | ((u32)(d & 1023) << 16);
        } else {
            int q = atomicAdd(ovfcur, 1);
            if (q < OVFCAP) ovf[q] = (u32)s | ((u32)d << 16);
        }
    }
}

// per-block exclusive scan -> row_start (local), block sums -> bsum
__global__ void k_partial(const int* __restrict__ cnt, int* __restrict__ row_start,
                          int* __restrict__ bsum, int n) {
    __shared__ int sd[256];
    int tid = threadIdx.x;
    int i = blockIdx.x * 256 + tid;
    int v = (i < n) ? cnt[i] : 0;
    sd[tid] = v;
    __syncthreads();
    for (int s = 1; s < 256; s <<= 1) {
        int t = (tid >= s) ? sd[tid - s] : 0;
        __syncthreads();
        sd[tid] += t;
        __syncthreads();
    }
    if (i < n) row_start[i] = sd[tid] - v;   // local exclusive
    if (tid == 255) bsum[blockIdx.x] = sd[255];
}
// add block-prefix (per-block 256-wide reduce), init cursor/dinv
__global__ void k_scanadd(const int* __restrict__ cnt, int* __restrict__ row_start,
                          int* __restrict__ cursor, const int* __restrict__ bsum,
                          float* __restrict__ dinv, int n, int nb, int E) {
    __shared__ int sd[256];
    int tid = threadIdx.x;
    int bid = blockIdx.x;
    sd[tid] = (tid < nb && tid < bid) ? bsum[tid] : 0;
    __syncthreads();
    for (int s = 128; s > 0; s >>= 1) {
        if (tid < s) sd[tid] += sd[tid + s];
        __syncthreads();
    }
    int off = sd[0];
    int i = bid * 256 + tid;
    if (i < n) {
        int rs = row_start[i] + off;
        row_start[i] = rs;
        cursor[i] = rs;
        dinv[i] = rsqrtf((float)(cnt[i] + 1));   // +1 self-loop
    }
    if (bid == 0 && tid == 0) row_start[n] = E;
}

// Fused: [0,nbuck) phase-B CSR fill (one block per bucket -> XCD-local csr window)
//      | [nbuck,nbuck+17) weight-canonicalize | rest scale-x -> gxt (in d_out).
// wc layout (u16): [0,8192) W1t[n*64+k] | [8192,16384) W2t[n*128+k]
//                  [16384,16512) b1 | [16512,16576) b2
__global__ __launch_bounds__(256) void k_prep(
    const u32* __restrict__ staging, const int* __restrict__ gcur,
    const u32* __restrict__ ovf, const int* __restrict__ ovfcur,
    int* __restrict__ cursor, u16* __restrict__ csr, int nbuck,
    const void* __restrict__ W1, const void* __restrict__ b1,
    const void* __restrict__ W2, const void* __restrict__ b2,
    u16* __restrict__ wc,
    const void* __restrict__ x, const float* __restrict__ dinv,
    u16* __restrict__ gxt, int n16) {
    __shared__ float sflag;
    const int bid = blockIdx.x;
    const int tid = threadIdx.x;
    if (bid < nbuck) {
        int b = bid;
        int used = min(gcur[b], CAP);
        const u32* st = staging + (size_t)b * CAP;
        for (int i0 = tid * 8; i0 < used; i0 += 2048) {
#pragma unroll
            for (int k = 0; k < 8; k++) {
                int i = i0 + k;
                if (i < used) {
                    u32 pk = st[i];
                    int d = (b << 10) | (int)(pk >> 16);
                    int p = atomicAdd(&cursor[d], 1);
                    csr[p] = (u16)(pk & 0xFFFFu);
                }
            }
        }
        int no = min(ovfcur[0], OVFCAP);
        for (int i = tid; i < no; i += 256) {
            u32 pk = ovf[i];
            int d = (int)(pk >> 16);
            if ((d >> 10) == b) {
                int p = atomicAdd(&cursor[d], 1);
                csr[p] = (u16)(pk & 0xFFFFu);
            }
        }
    } else if (bid < nbuck + 17) {
        bool isbf = block_isbf((const u16*)x, &sflag);
        int cb = bid - nbuck;
        for (int i = cb * 256 + tid; i < 16576; i += 17 * 256) {
            const void* s; int off;
            if (i < 8192)       { int nn = i >> 6, k = i & 63;  s = W1; off = k * 128 + nn; }
            else if (i < 16384) { int j = i - 8192; int nn = j >> 7, k = j & 127; s = W2; off = k * 64 + nn; }
            else if (i < 16512) { s = b1; off = i - 16384; }
            else                { s = b2; off = i - 16512; }
            wc[i] = isbf ? ((const u16*)s)[off] : f2bf(((const float*)s)[off]);
        }
    } else {
        // xt = bf16(x * dinv[row]) -> gxt (d_out scratch)
        bool isbf = block_isbf((const u16*)x, &sflag);
        int idx = (bid - nbuck - 17) * 256 + tid;
        if (idx >= n16) return;
        int r = idx >> 4;
        float di = dinv[r];
        float4 v;
        if (isbf) {
            ushort4 u = ((const ushort4*)x)[idx];
            v.x = bf2f(u.x); v.y = bf2f(u.y); v.z = bf2f(u.z); v.w = bf2f(u.w);
        } else {
            v = ((const float4*)x)[idx];
        }
        ushort4 o;
        o.x = f2bf(v.x * di); o.y = f2bf(v.y * di);
        o.z = f2bf(v.z * di); o.w = f2bf(v.w * di);
        ((ushort4*)gxt)[idx] = o;
    }
}

// gather: out[d] = feat[d] + sum_{j in in(d)} feat[csr[j]]  (32 lanes/node)
template<bool FINAL>
__global__ __launch_bounds__(256) void k_gather(
    const u32* __restrict__ feat, const int* __restrict__ row_start,
    const u16* __restrict__ csr, const float* __restrict__ dinv,
    const u16* __restrict__ b2c, const void* __restrict__ xdet,
    void* __restrict__ outp, int n) {
    __shared__ float sflag;
    bool isbf = true;
    if (FINAL) isbf = block_isbf((const u16*)xdet, &sflag);
    int t = blockIdx.x * 256 + threadIdx.x;
    int d = t >> 5;
    int lane = t & 31;
    if (d >= n) return;
    const u32* fl = feat + lane;
    u32 w = fl[(size_t)d * 32];                 // self-loop
    float ax = bf2f((u16)(w & 0xFFFFu));
    float ay = bf2f((u16)(w >> 16));
    gather_accum(fl, csr, row_start[d], row_start[d + 1], lane, ax, ay);
    if (FINAL) {
        float di = dinv[d];
        ax = ax * di + bf2f(b2c[2 * lane + 0]);
        ay = ay * di + bf2f(b2c[2 * lane + 1]);
        if (isbf) {
            u32 o = (u32)f2bf(ax) | ((u32)f2bf(ay) << 16);
            ((u32*)outp)[(size_t)d * 32 + lane] = o;
        } else {
            ((float2*)outp)[(size_t)d * 32 + lane] = make_float2(ax, ay);
        }
    } else {
        u32 o = (u32)f2bf(ax) | ((u32)f2bf(ay) << 16);
        ((u32*)outp)[(size_t)d * 32 + lane] = o;
    }
}

// MFMA fused 2-layer MLP on a 32-row tile (53 KB LDS -> 3 blocks/CU), in-place safe:
//   h   = relu( bf16(dinv[r]*acc1[r,:]) @ W1 + b1 )   [32 x 128]
//   ht2 = ( h @ W2 ) * dinv[r]                        [32 x 64]  -> bf16 outb
__global__ __launch_bounds__(256) void k_mlp(
    const u16* __restrict__ accin, const u16* __restrict__ wc,
    const float* __restrict__ dinv, u16* outb, int n) {
    __shared__ __align__(16) u16 As[32 * 72];      //  4.5 KB
    __shared__ __align__(16) u16 W1t[128 * 72];    // 18.0 KB
    __shared__ __align__(16) u16 W2t[64 * 136];    // 17.0 KB
    __shared__ __align__(16) u16 Hs[32 * 136];     //  8.5 KB
    __shared__ float b1s[128];
    __shared__ float dvs[32];
    const int tid = threadIdx.x;
    const int row0 = blockIdx.x * 32;

    if (tid < 32) {
        int r = row0 + tid;
        dvs[tid] = (r < n) ? dinv[r] : 0.f;
    } else if (tid < 160) {
        b1s[tid - 32] = bf2f(wc[16384 + tid - 32]);
    }
    for (int i = tid; i < 1024; i += 256) {
        int r = i >> 5, kk = i & 31;
        int row = row0 + r;
        u32 v = 0;
        if (row < n) {
            u32 g = ((const u32*)accin)[(size_t)row * 32 + kk];
            float di = dinv[row];
            u16 lo = f2bf(bf2f((u16)(g & 0xFFFFu)) * di);
            u16 hi = f2bf(bf2f((u16)(g >> 16)) * di);
            v = (u32)lo | ((u32)hi << 16);
        }
        *(u32*)&As[r * 72 + kk * 2] = v;
    }
    for (int i = tid; i < 4096; i += 256) {
        int nn = i >> 5, kk = i & 31;
        *(u32*)&W1t[nn * 72 + kk * 2] = ((const u32*)wc)[i];
    }
    for (int i = tid; i < 4096; i += 256) {
        int nn = i >> 6, kk = i & 63;
        *(u32*)&W2t[nn * 136 + kk * 2] = ((const u32*)wc)[4096 + i];
    }
    __syncthreads();

    const int wave = tid >> 6;     // 0..3
    const int lane = tid & 63;
    const int q = lane >> 4;       // quad
    const int ln = lane & 15;

    // ---- GEMM1: [32x64] @ [64x128] ----
    bf16x8 a[2][2];
#pragma unroll
    for (int mt = 0; mt < 2; mt++)
#pragma unroll
        for (int ks = 0; ks < 2; ks++)
            a[mt][ks] = *(const bf16x8*)&As[(mt * 16 + ln) * 72 + ks * 32 + q * 8];

    f32x4 c1[2][2];   // [ntl][mt]
#pragma unroll
    for (int ntl = 0; ntl < 2; ntl++)
#pragma unroll
        for (int mt = 0; mt < 2; mt++) c1[ntl][mt] = (f32x4){0.f, 0.f, 0.f, 0.f};

#pragma unroll
    for (int ntl = 0; ntl < 2; ntl++) {
        int nt = wave * 2 + ntl;
        bf16x8 b0 = *(const bf16x8*)&W1t[(nt * 16 + ln) * 72 + 0 + q * 8];
        bf16x8 b1f = *(const bf16x8*)&W1t[(nt * 16 + ln) * 72 + 32 + q * 8];
#pragma unroll
        for (int mt = 0; mt < 2; mt++) {
            c1[ntl][mt] = __builtin_amdgcn_mfma_f32_16x16x32_bf16(a[mt][0], b0, c1[ntl][mt], 0, 0, 0);
            c1[ntl][mt] = __builtin_amdgcn_mfma_f32_16x16x32_bf16(a[mt][1], b1f, c1[ntl][mt], 0, 0, 0);
        }
    }
#pragma unroll
    for (int ntl = 0; ntl < 2; ntl++) {
        int col = (wave * 2 + ntl) * 16 + ln;
        float bb = b1s[col];
#pragma unroll
        for (int mt = 0; mt < 2; mt++)
#pragma unroll
            for (int r = 0; r < 4; r++) {
                int hrow = mt * 16 + q * 4 + r;
                Hs[hrow * 136 + col] = f2bf(fmaxf(c1[ntl][mt][r] + bb, 0.f));
            }
    }
    __syncthreads();

    // ---- GEMM2: [32x128] @ [128x64] ----
    f32x4 c2[2];
    c2[0] = (f32x4){0.f, 0.f, 0.f, 0.f};
    c2[1] = (f32x4){0.f, 0.f, 0.f, 0.f};
#pragma unroll
    for (int ks = 0; ks < 4; ks++) {
        bf16x8 bb = *(const bf16x8*)&W2t[(wave * 16 + ln) * 136 + ks * 32 + q * 8];
#pragma unroll
        for (int mt = 0; mt < 2; mt++) {
            bf16x8 aa = *(const bf16x8*)&Hs[(mt * 16 + ln) * 136 + ks * 32 + q * 8];
            c2[mt] = __builtin_amdgcn_mfma_f32_16x16x32_bf16(aa, bb, c2[mt], 0, 0, 0);
        }
    }
#pragma unroll
    for (int mt = 0; mt < 2; mt++)
#pragma unroll
        for (int r = 0; r < 4; r++) {
            int rloc = mt * 16 + q * 4 + r;
            int row = row0 + rloc;
            if (row < n) {
                int col = wave * 16 + ln;
                outb[(size_t)row * 64 + col] = f2bf(c2[mt][r] * dvs[rloc]);
            }
        }
}

extern "C" void kernel_launch(void* const* d_in, const int* in_sizes, int n_in,
                              void* d_out, int out_size, void* d_ws, size_t ws_size,
                              hipStream_t stream) {
    const void* x  = d_in[0];
    const int* ei  = (const int*)d_in[1];
    const void* W1 = d_in[2];
    const void* b1 = d_in[3];
    const void* W2 = d_in[4];
    const void* b2 = d_in[5];

    const int N = in_sizes[0] / 64;   // 50000 (< 65536 required: u16 csr + packing)
    const int E = in_sizes[1] / 2;    // 800000
    const int* src = ei;
    const int* dst = ei + E;

    // workspace (~8.9 MB):
    //   dinv[NP] | cnt[N] | gcur[64] | ovfcur+pad[64] | row_start[N+64] | cursor[N]
    //   | bsum[256] | ovf[4096] u32 | csr[E] u16 | wc[16576] u16 | bufB (N*64 u16)
    // staging (nbuck*CAP u32 <= 5.24 MB) aliases bufB (dead until k_mlp writes it).
    // xt lives in d_out (scratch until k_gather<true> rewrites it).
    float* ws = (float*)d_ws;
    const int NP = ((N + 64) + 63) & ~63;
    float* dinv    = ws;
    int* cnt       = (int*)(ws + NP);
    int* gcur      = cnt + N;
    int* ovfcur    = gcur + 64;
    int* row_start = gcur + 128;
    int* cursor    = row_start + ((N + 64) & ~63);
    int* bsum      = cursor + N;
    u32* ovf       = (u32*)(bsum + 256);
    u16* csr       = (u16*)(ovf + OVFCAP);
    u16* wc        = (u16*)(((size_t)(csr + E) + 255) & ~(size_t)255);
    u16* bufB      = (u16*)(((size_t)(wc + 16576) + 255) & ~(size_t)255);
    u32* staging   = (u32*)bufB;
    u16* gxt       = (u16*)d_out;

    const int n16 = N * 16;
    const int nb = (N + 255) / 256;            // 196 (<=256 required)
    const int gth = (N * 32 + 255) / 256;      // gather grid
    const int nbuck = (N + 1023) >> 10;        // 49 (<=64 required)
    const int binB = (E + CHUNK - 1) / CHUNK;  // 196
    const int prepB = nbuck + 17 + (n16 + 255) / 256;
    dim3 blk(256);

    // zero cnt + gcur + ovfcur in one memset (graph-capture legal)
    hipMemsetAsync(cnt, 0, (size_t)(N + 128) * sizeof(int), stream);
    // degree count + bucket-binning
    k_binA<<<dim3(binB), blk, 0, stream>>>(src, dst, cnt, gcur, staging, ovf, ovfcur, E);
    k_partial<<<dim3(nb), blk, 0, stream>>>(cnt, row_start, bsum, N);
    k_scanadd<<<dim3(nb), blk, 0, stream>>>(cnt, row_start, cursor, bsum, dinv, N, nb, E);
    // phase-B csr fill (XCD-local per bucket) + weight canonicalize + xt=bf16(x*dinv)
    k_prep<<<dim3(prepB), blk, 0, stream>>>(staging, gcur, ovf, ovfcur, cursor, csr,
                                            nbuck, W1, b1, W2, b2, wc, x, dinv, gxt, n16);
    // acc1 = gather(xt) -> bufB (staging now dead)
    k_gather<false><<<dim3(gth), blk, 0, stream>>>((const u32*)gxt, row_start, csr,
                                                   dinv, wc + 16512, x, bufB, N);
    // ht2 = (relu(dinv*acc1 @ W1 + b1) @ W2)*dinv -> bufB (in-place, row-local)
    k_mlp<<<dim3((N + 31) / 32), blk, 0, stream>>>((const u16*)bufB, wc, dinv, bufB, N);
    // out = bf16( (ht2[d]+gather(ht2))*dinv + b2 ) -> d_out
    k_gather<true><<<dim3(gth), blk, 0, stream>>>((const u32*)bufB, row_start, csr,
                                                  dinv, wc + 16512, x, d_out, N);
}

// Round 9
// 202.201 us; speedup vs baseline: 1.1092x; 1.1092x over previous
//
#include <hip/hip_runtime.h>

typedef unsigned short u16;
typedef unsigned int u32;

typedef __attribute__((ext_vector_type(8))) short bf16x8;
typedef __attribute__((ext_vector_type(4))) float f32x4;

#define CAP 20480      // staging capacity per bucket (mean ~16384 at E=800k, +32 sigma)
#define OVFCAP 4096
#define CHUNK 4096     // edges per binA block
#define SLICES 8       // fill blocks per bucket in phase B

__device__ __forceinline__ float bf2f(u16 u) {
    return __uint_as_float(((u32)u) << 16);
}
__device__ __forceinline__ u16 f2bf(float f) {
    u32 x = __float_as_uint(f);
    return (u16)((x + 0x7fffu + ((x >> 16) & 1u)) >> 16);
}

// block-uniform dtype flag: true if x is bf16, false if fp32.
__device__ __forceinline__ bool block_isbf(const u16* __restrict__ x, float* sflag) {
    int tid = threadIdx.x;
    if (tid < 64) {
        u16 v = x[tid * 2];
        u32 ex = (v >> 7) & 0xFFu;
        unsigned long long m = __ballot(ex >= 90u && ex <= 140u);
        if (tid == 0) *sflag = (m == ~0ull) ? 1.0f : 0.0f;
    }
    __syncthreads();
    return *sflag != 0.0f;
}

// 32-lane-group gather accumulate: ax,ay += feats of rows csr[s0..s1) at u32-col `lane`.
__device__ __forceinline__ void gather_accum(
    const u32* __restrict__ fl, const u16* __restrict__ csr,
    int s0, int s1, int lane, float& ax, float& ay) {
    int deg = s1 - s0;
    for (int base = 0; base < deg; base += 32) {
        int m = min(deg - base, 32);
        int idx = 0;
        if (lane < m) idx = (int)csr[s0 + base + lane];
        int j = 0;
        for (; j + 8 <= m; j += 8) {
            u32 wv[8];
#pragma unroll
            for (int u = 0; u < 8; u++) {
                int sv = __shfl(idx, j + u, 32);
                wv[u] = fl[(size_t)sv * 32];
            }
#pragma unroll
            for (int u = 0; u < 8; u++) {
                ax += bf2f((u16)(wv[u] & 0xFFFFu));
                ay += bf2f((u16)(wv[u] >> 16));
            }
        }
        for (; j + 4 <= m; j += 4) {
            u32 wv[4];
#pragma unroll
            for (int u = 0; u < 4; u++) {
                int sv = __shfl(idx, j + u, 32);
                wv[u] = fl[(size_t)sv * 32];
            }
#pragma unroll
            for (int u = 0; u < 4; u++) {
                ax += bf2f((u16)(wv[u] & 0xFFFFu));
                ay += bf2f((u16)(wv[u] >> 16));
            }
        }
        for (; j < m; j++) {
            int sv = __shfl(idx, j, 32);
            u32 wa = fl[(size_t)sv * 32];
            ax += bf2f((u16)(wa & 0xFFFFu));
            ay += bf2f((u16)(wa >> 16));
        }
    }
}

// Phase A: per-node degree count + bucket-binning of edges into staging.
// bucket(d) = d >> 10 (1024 nodes per bucket). Packed entry: src | (d&1023)<<16.
__global__ __launch_bounds__(256) void k_binA(
    const int* __restrict__ src, const int* __restrict__ dst,
    int* __restrict__ cnt, int* __restrict__ gcur,
    u32* __restrict__ staging, u32* __restrict__ ovf, int* __restrict__ ovfcur,
    int E) {
    __shared__ int hcnt[64];
    __shared__ int hbase[64];
    const int tid = threadIdx.x;
    const int e0 = blockIdx.x * CHUNK;
    const int e1 = min(e0 + CHUNK, E);
    if (tid < 64) hcnt[tid] = 0;
    __syncthreads();
    for (int e = e0 + tid; e < e1; e += 256) {
        int d = dst[e];
        atomicAdd(&cnt[d], 1);          // per-node in-degree (global)
        atomicAdd(&hcnt[d >> 10], 1);   // LDS bucket histogram
    }
    __syncthreads();
    if (tid < 64) {
        int c = hcnt[tid];
        hbase[tid] = (c > 0) ? atomicAdd(&gcur[tid], c) : 0;
        hcnt[tid] = 0;                   // reuse as local cursor
    }
    __syncthreads();
    for (int e = e0 + tid; e < e1; e += 256) {
        int d = dst[e];
        int s = src[e];
        int b = d >> 10;
        int r = atomicAdd(&hcnt[b], 1);  // LDS rank
        int p = hbase[b] + r;
        if (p < CAP) {
            staging[(size_t)b * CAP + p] = (u32)s | ((u32)(d & 1023) << 16);
        } else {
            int q = atomicAdd(ovfcur, 1);
            if (q < OVFCAP) ovf[q] = (u32)s | ((u32)d << 16);
        }
    }
}

// per-block exclusive scan -> row_start (local), block sums -> bsum
__global__ void k_partial(const int* __restrict__ cnt, int* __restrict__ row_start,
                          int* __restrict__ bsum, int n) {
    __shared__ int sd[256];
    int tid = threadIdx.x;
    int i = blockIdx.x * 256 + tid;
    int v = (i < n) ? cnt[i] : 0;
    sd[tid] = v;
    __syncthreads();
    for (int s = 1; s < 256; s <<= 1) {
        int t = (tid >= s) ? sd[tid - s] : 0;
        __syncthreads();
        sd[tid] += t;
        __syncthreads();
    }
    if (i < n) row_start[i] = sd[tid] - v;   // local exclusive
    if (tid == 255) bsum[blockIdx.x] = sd[255];
}
// add block-prefix (per-block 256-wide reduce), init cursor/dinv
__global__ void k_scanadd(const int* __restrict__ cnt, int* __restrict__ row_start,
                          int* __restrict__ cursor, const int* __restrict__ bsum,
                          float* __restrict__ dinv, int n, int nb, int E) {
    __shared__ int sd[256];
    int tid = threadIdx.x;
    int bid = blockIdx.x;
    sd[tid] = (tid < nb && tid < bid) ? bsum[tid] : 0;
    __syncthreads();
    for (int s = 128; s > 0; s >>= 1) {
        if (tid < s) sd[tid] += sd[tid + s];
        __syncthreads();
    }
    int off = sd[0];
    int i = bid * 256 + tid;
    if (i < n) {
        int rs = row_start[i] + off;
        row_start[i] = rs;
        cursor[i] = rs;
        dinv[i] = rsqrtf((float)(cnt[i] + 1));   // +1 self-loop
    }
    if (bid == 0 && tid == 0) row_start[n] = E;
}

// Fused: [0,nbuck*SLICES) phase-B CSR fill (SLICES blocks per bucket slice the
// staging range; csr window per bucket stays L2-compact)
//      | next 17: weight-canonicalize | rest: scale-x -> gxt (in d_out).
// wc layout (u16): [0,8192) W1t[n*64+k] | [8192,16384) W2t[n*128+k]
//                  [16384,16512) b1 | [16512,16576) b2
__global__ __launch_bounds__(256) void k_prep(
    const u32* __restrict__ staging, const int* __restrict__ gcur,
    const u32* __restrict__ ovf, const int* __restrict__ ovfcur,
    int* __restrict__ cursor, u16* __restrict__ csr, int nbuck,
    const void* __restrict__ W1, const void* __restrict__ b1,
    const void* __restrict__ W2, const void* __restrict__ b2,
    u16* __restrict__ wc,
    const void* __restrict__ x, const float* __restrict__ dinv,
    u16* __restrict__ gxt, int n16) {
    __shared__ float sflag;
    const int bid = blockIdx.x;
    const int tid = threadIdx.x;
    const int fillB = nbuck * SLICES;
    if (bid < fillB) {
        int b = bid / SLICES;
        int sl = bid - b * SLICES;
        int used = min(gcur[b], CAP);
        int lo = (used * sl) / SLICES;
        int hi = (used * (sl + 1)) / SLICES;
        const u32* st = staging + (size_t)b * CAP;
        for (int i = lo + tid; i < hi; i += 256) {
            u32 pk = st[i];
            int d = (b << 10) | (int)(pk >> 16);
            int p = atomicAdd(&cursor[d], 1);
            csr[p] = (u16)(pk & 0xFFFFu);
        }
        if (sl == 0) {
            int no = min(ovfcur[0], OVFCAP);
            for (int i = tid; i < no; i += 256) {
                u32 pk = ovf[i];
                int d = (int)(pk >> 16);
                if ((d >> 10) == b) {
                    int p = atomicAdd(&cursor[d], 1);
                    csr[p] = (u16)(pk & 0xFFFFu);
                }
            }
        }
    } else if (bid < fillB + 17) {
        bool isbf = block_isbf((const u16*)x, &sflag);
        int cb = bid - fillB;
        for (int i = cb * 256 + tid; i < 16576; i += 17 * 256) {
            const void* s; int off;
            if (i < 8192)       { int nn = i >> 6, k = i & 63;  s = W1; off = k * 128 + nn; }
            else if (i < 16384) { int j = i - 8192; int nn = j >> 7, k = j & 127; s = W2; off = k * 64 + nn; }
            else if (i < 16512) { s = b1; off = i - 16384; }
            else                { s = b2; off = i - 16512; }
            wc[i] = isbf ? ((const u16*)s)[off] : f2bf(((const float*)s)[off]);
        }
    } else {
        // xt = bf16(x * dinv[row]) -> gxt (d_out scratch)
        bool isbf = block_isbf((const u16*)x, &sflag);
        int idx = (bid - fillB - 17) * 256 + tid;
        if (idx >= n16) return;
        int r = idx >> 4;
        float di = dinv[r];
        float4 v;
        if (isbf) {
            ushort4 u = ((const ushort4*)x)[idx];
            v.x = bf2f(u.x); v.y = bf2f(u.y); v.z = bf2f(u.z); v.w = bf2f(u.w);
        } else {
            v = ((const float4*)x)[idx];
        }
        ushort4 o;
        o.x = f2bf(v.x * di); o.y = f2bf(v.y * di);
        o.z = f2bf(v.z * di); o.w = f2bf(v.w * di);
        ((ushort4*)gxt)[idx] = o;
    }
}

// gather: out[d] = feat[d] + sum_{j in in(d)} feat[csr[j]]  (32 lanes/node)
template<bool FINAL>
__global__ __launch_bounds__(256) void k_gather(
    const u32* __restrict__ feat, const int* __restrict__ row_start,
    const u16* __restrict__ csr, const float* __restrict__ dinv,
    const u16* __restrict__ b2c, const void* __restrict__ xdet,
    void* __restrict__ outp, int n) {
    __shared__ float sflag;
    bool isbf = true;
    if (FINAL) isbf = block_isbf((const u16*)xdet, &sflag);
    int t = blockIdx.x * 256 + threadIdx.x;
    int d = t >> 5;
    int lane = t & 31;
    if (d >= n) return;
    const u32* fl = feat + lane;
    u32 w = fl[(size_t)d * 32];                 // self-loop
    float ax = bf2f((u16)(w & 0xFFFFu));
    float ay = bf2f((u16)(w >> 16));
    gather_accum(fl, csr, row_start[d], row_start[d + 1], lane, ax, ay);
    if (FINAL) {
        float di = dinv[d];
        ax = ax * di + bf2f(b2c[2 * lane + 0]);
        ay = ay * di + bf2f(b2c[2 * lane + 1]);
        if (isbf) {
            u32 o = (u32)f2bf(ax) | ((u32)f2bf(ay) << 16);
            ((u32*)outp)[(size_t)d * 32 + lane] = o;
        } else {
            ((float2*)outp)[(size_t)d * 32 + lane] = make_float2(ax, ay);
        }
    } else {
        u32 o = (u32)f2bf(ax) | ((u32)f2bf(ay) << 16);
        ((u32*)outp)[(size_t)d * 32 + lane] = o;
    }
}

// MFMA fused 2-layer MLP on a 32-row tile (53 KB LDS -> 3 blocks/CU), in-place safe:
//   h   = relu( bf16(dinv[r]*acc1[r,:]) @ W1 + b1 )   [32 x 128]
//   ht2 = ( h @ W2 ) * dinv[r]                        [32 x 64]  -> bf16 outb
__global__ __launch_bounds__(256) void k_mlp(
    const u16* __restrict__ accin, const u16* __restrict__ wc,
    const float* __restrict__ dinv, u16* outb, int n) {
    __shared__ __align__(16) u16 As[32 * 72];      //  4.5 KB
    __shared__ __align__(16) u16 W1t[128 * 72];    // 18.0 KB
    __shared__ __align__(16) u16 W2t[64 * 136];    // 17.0 KB
    __shared__ __align__(16) u16 Hs[32 * 136];     //  8.5 KB
    __shared__ float b1s[128];
    __shared__ float dvs[32];
    const int tid = threadIdx.x;
    const int row0 = blockIdx.x * 32;

    if (tid < 32) {
        int r = row0 + tid;
        dvs[tid] = (r < n) ? dinv[r] : 0.f;
    } else if (tid < 160) {
        b1s[tid - 32] = bf2f(wc[16384 + tid - 32]);
    }
    for (int i = tid; i < 1024; i += 256) {
        int r = i >> 5, kk = i & 31;
        int row = row0 + r;
        u32 v = 0;
        if (row < n) {
            u32 g = ((const u32*)accin)[(size_t)row * 32 + kk];
            float di = dinv[row];
            u16 lo = f2bf(bf2f((u16)(g & 0xFFFFu)) * di);
            u16 hi = f2bf(bf2f((u16)(g >> 16)) * di);
            v = (u32)lo | ((u32)hi << 16);
        }
        *(u32*)&As[r * 72 + kk * 2] = v;
    }
    for (int i = tid; i < 4096; i += 256) {
        int nn = i >> 5, kk = i & 31;
        *(u32*)&W1t[nn * 72 + kk * 2] = ((const u32*)wc)[i];
    }
    for (int i = tid; i < 4096; i += 256) {
        int nn = i >> 6, kk = i & 63;
        *(u32*)&W2t[nn * 136 + kk * 2] = ((const u32*)wc)[4096 + i];
    }
    __syncthreads();

    const int wave = tid >> 6;     // 0..3
    const int lane = tid & 63;
    const int q = lane >> 4;       // quad
    const int ln = lane & 15;

    // ---- GEMM1: [32x64] @ [64x128] ----
    bf16x8 a[2][2];
#pragma unroll
    for (int mt = 0; mt < 2; mt++)
#pragma unroll
        for (int ks = 0; ks < 2; ks++)
            a[mt][ks] = *(const bf16x8*)&As[(mt * 16 + ln) * 72 + ks * 32 + q * 8];

    f32x4 c1[2][2];   // [ntl][mt]
#pragma unroll
    for (int ntl = 0; ntl < 2; ntl++)
#pragma unroll
        for (int mt = 0; mt < 2; mt++) c1[ntl][mt] = (f32x4){0.f, 0.f, 0.f, 0.f};

#pragma unroll
    for (int ntl = 0; ntl < 2; ntl++) {
        int nt = wave * 2 + ntl;
        bf16x8 b0 = *(const bf16x8*)&W1t[(nt * 16 + ln) * 72 + 0 + q * 8];
        bf16x8 b1f = *(const bf16x8*)&W1t[(nt * 16 + ln) * 72 + 32 + q * 8];
#pragma unroll
        for (int mt = 0; mt < 2; mt++) {
            c1[ntl][mt] = __builtin_amdgcn_mfma_f32_16x16x32_bf16(a[mt][0], b0, c1[ntl][mt], 0, 0, 0);
            c1[ntl][mt] = __builtin_amdgcn_mfma_f32_16x16x32_bf16(a[mt][1], b1f, c1[ntl][mt], 0, 0, 0);
        }
    }
#pragma unroll
    for (int ntl = 0; ntl < 2; ntl++) {
        int col = (wave * 2 + ntl) * 16 + ln;
        float bb = b1s[col];
#pragma unroll
        for (int mt = 0; mt < 2; mt++)
#pragma unroll
            for (int r = 0; r < 4; r++) {
                int hrow = mt * 16 + q * 4 + r;
                Hs[hrow * 136 + col] = f2bf(fmaxf(c1[ntl][mt][r] + bb, 0.f));
            }
    }
    __syncthreads();

    // ---- GEMM2: [32x128] @ [128x64] ----
    f32x4 c2[2];
    c2[0] = (f32x4){0.f, 0.f, 0.f, 0.f};
    c2[1] = (f32x4){0.f, 0.f, 0.f, 0.f};
#pragma unroll
    for (int ks = 0; ks < 4; ks++) {
        bf16x8 bb = *(const bf16x8*)&W2t[(wave * 16 + ln) * 136 + ks * 32 + q * 8];
#pragma unroll
        for (int mt = 0; mt < 2; mt++) {
            bf16x8 aa = *(const bf16x8*)&Hs[(mt * 16 + ln) * 136 + ks * 32 + q * 8];
            c2[mt] = __builtin_amdgcn_mfma_f32_16x16x32_bf16(aa, bb, c2[mt], 0, 0, 0);
        }
    }
#pragma unroll
    for (int mt = 0; mt < 2; mt++)
#pragma unroll
        for (int r = 0; r < 4; r++) {
            int rloc = mt * 16 + q * 4 + r;
            int row = row0 + rloc;
            if (row < n) {
                int col = wave * 16 + ln;
                outb[(size_t)row * 64 + col] = f2bf(c2[mt][r] * dvs[rloc]);
            }
        }
}

extern "C" void kernel_launch(void* const* d_in, const int* in_sizes, int n_in,
                              void* d_out, int out_size, void* d_ws, size_t ws_size,
                              hipStream_t stream) {
    const void* x  = d_in[0];
    const int* ei  = (const int*)d_in[1];
    const void* W1 = d_in[2];
    const void* b1 = d_in[3];
    const void* W2 = d_in[4];
    const void* b2 = d_in[5];

    const int N = in_sizes[0] / 64;   // 50000 (< 65536 required: u16 csr + packing)
    const int E = in_sizes[1] / 2;    // 800000
    const int* src = ei;
    const int* dst = ei + E;

    // workspace (~8.9 MB of the 256 MiB d_ws):
    //   dinv[NP] | cnt[N] | gcur[64] | ovfcur+pad[64] | row_start[N+64] | cursor[N]
    //   | bsum[256] | ovf[4096] u32 | csr[E] u16 | wc[16576] u16 | bufB (N*64 u16)
    // staging (nbuck*CAP u32 <= 5.24 MB) aliases bufB (dead until k_mlp writes it).
    // xt lives in d_out (scratch until k_gather<true> rewrites it).
    float* ws = (float*)d_ws;
    const int NP = ((N + 64) + 63) & ~63;
    float* dinv    = ws;
    int* cnt       = (int*)(ws + NP);
    int* gcur      = cnt + N;
    int* ovfcur    = gcur + 64;
    int* row_start = gcur + 128;
    int* cursor    = row_start + ((N + 64) & ~63);
    int* bsum      = cursor + N;
    u32* ovf       = (u32*)(bsum + 256);
    u16* csr       = (u16*)(ovf + OVFCAP);
    u16* wc        = (u16*)(((size_t)(csr + E) + 255) & ~(size_t)255);
    u16* bufB      = (u16*)(((size_t)(wc + 16576) + 255) & ~(size_t)255);
    u32* staging   = (u32*)bufB;
    u16* gxt       = (u16*)d_out;

    const int n16 = N * 16;
    const int nb = (N + 255) / 256;            // 196 (<=256 required)
    const int gth = (N * 32 + 255) / 256;      // gather grid
    const int nbuck = (N + 1023) >> 10;        // 49 (<=64 required)
    const int binB = (E + CHUNK - 1) / CHUNK;  // 196
    const int prepB = nbuck * SLICES + 17 + (n16 + 255) / 256;
    dim3 blk(256);

    // zero cnt + gcur + ovfcur in one memset (graph-capture legal)
    hipMemsetAsync(cnt, 0, (size_t)(N + 128) * sizeof(int), stream);
    // degree count + bucket-binning
    k_binA<<<dim3(binB), blk, 0, stream>>>(src, dst, cnt, gcur, staging, ovf, ovfcur, E);
    k_partial<<<dim3(nb), blk, 0, stream>>>(cnt, row_start, bsum, N);
    k_scanadd<<<dim3(nb), blk, 0, stream>>>(cnt, row_start, cursor, bsum, dinv, N, nb, E);
    // phase-B csr fill (sliced per bucket) + weight canonicalize + xt=bf16(x*dinv)
    k_prep<<<dim3(prepB), blk, 0, stream>>>(staging, gcur, ovf, ovfcur, cursor, csr,
                                            nbuck, W1, b1, W2, b2, wc, x, dinv, gxt, n16);
    // acc1 = gather(xt) -> bufB (staging now dead)
    k_gather<false><<<dim3(gth), blk, 0, stream>>>((const u32*)gxt, row_start, csr,
                                                   dinv, wc + 16512, x, bufB, N);
    // ht2 = (relu(dinv*acc1 @ W1 + b1) @ W2)*dinv -> bufB (in-place, row-local)
    k_mlp<<<dim3((N + 31) / 32), blk, 0, stream>>>((const u16*)bufB, wc, dinv, bufB, N);
    // out = bf16( (ht2[d]+gather(ht2))*dinv + b2 ) -> d_out
    k_gather<true><<<dim3(gth), blk, 0, stream>>>((const u32*)bufB, row_start, csr,
                                                  dinv, wc + 16512, x, d_out, N);
}

// Round 10
// 158.904 us; speedup vs baseline: 1.4114x; 1.2725x over previous
//
#include <hip/hip_runtime.h>

typedef unsigned short u16;
typedef unsigned int u32;

typedef __attribute__((ext_vector_type(8))) short bf16x8;
typedef __attribute__((ext_vector_type(4))) float f32x4;

#define BSH 8          // bucket shift: 256 nodes per bucket
#define CAP 5120       // staging capacity per bucket (mean 4081 at E=800k, +16 sigma)
#define OVFCAP 8192
#define CHUNK 2048     // edges per binA2 block

__device__ __forceinline__ float bf2f(u16 u) {
    return __uint_as_float(((u32)u) << 16);
}
__device__ __forceinline__ u16 f2bf(float f) {
    u32 x = __float_as_uint(f);
    return (u16)((x + 0x7fffu + ((x >> 16) & 1u)) >> 16);
}

// block-uniform dtype flag: true if x is bf16, false if fp32.
__device__ __forceinline__ bool block_isbf(const u16* __restrict__ x, float* sflag) {
    int tid = threadIdx.x;
    if (tid < 64) {
        u16 v = x[tid * 2];
        u32 ex = (v >> 7) & 0xFFu;
        unsigned long long m = __ballot(ex >= 90u && ex <= 140u);
        if (tid == 0) *sflag = (m == ~0ull) ? 1.0f : 0.0f;
    }
    __syncthreads();
    return *sflag != 0.0f;
}

// 32-lane-group gather accumulate: ax,ay += feats of rows csr[s0..s1) at u32-col `lane`.
__device__ __forceinline__ void gather_accum(
    const u32* __restrict__ fl, const u16* __restrict__ csr,
    int s0, int s1, int lane, float& ax, float& ay) {
    int deg = s1 - s0;
    for (int base = 0; base < deg; base += 32) {
        int m = min(deg - base, 32);
        int idx = 0;
        if (lane < m) idx = (int)csr[s0 + base + lane];
        int j = 0;
        for (; j + 8 <= m; j += 8) {
            u32 wv[8];
#pragma unroll
            for (int u = 0; u < 8; u++) {
                int sv = __shfl(idx, j + u, 32);
                wv[u] = fl[(size_t)sv * 32];
            }
#pragma unroll
            for (int u = 0; u < 8; u++) {
                ax += bf2f((u16)(wv[u] & 0xFFFFu));
                ay += bf2f((u16)(wv[u] >> 16));
            }
        }
        for (; j + 4 <= m; j += 4) {
            u32 wv[4];
#pragma unroll
            for (int u = 0; u < 4; u++) {
                int sv = __shfl(idx, j + u, 32);
                wv[u] = fl[(size_t)sv * 32];
            }
#pragma unroll
            for (int u = 0; u < 4; u++) {
                ax += bf2f((u16)(wv[u] & 0xFFFFu));
                ay += bf2f((u16)(wv[u] >> 16));
            }
        }
        for (; j < m; j++) {
            int sv = __shfl(idx, j, 32);
            u32 wa = fl[(size_t)sv * 32];
            ax += bf2f((u16)(wa & 0xFFFFu));
            ay += bf2f((u16)(wa >> 16));
        }
    }
}

// Bin edges into per-bucket staging. NO per-node atomics. bucket(d) = d >> BSH.
// Packed entry: src | (d & 255) << 16.
__global__ __launch_bounds__(256) void k_binA2(
    const int* __restrict__ src, const int* __restrict__ dst,
    int* __restrict__ gcur, u32* __restrict__ staging,
    u32* __restrict__ ovf, int* __restrict__ ovfcur, int E) {
    __shared__ int hcnt[256];
    __shared__ int hbase[256];
    const int tid = threadIdx.x;
    const int e0 = blockIdx.x * CHUNK;
    const int e1 = min(e0 + CHUNK, E);
    hcnt[tid] = 0;
    __syncthreads();
    for (int e = e0 + tid; e < e1; e += 256)
        atomicAdd(&hcnt[dst[e] >> BSH], 1);
    __syncthreads();
    {
        int c = hcnt[tid];
        hbase[tid] = (c > 0) ? atomicAdd(&gcur[tid], c) : 0;
        hcnt[tid] = 0;                   // reuse as local cursor
    }
    __syncthreads();
    for (int e = e0 + tid; e < e1; e += 256) {
        int d = dst[e];
        int s = src[e];
        int b = d >> BSH;
        int r = atomicAdd(&hcnt[b], 1);
        int p = hbase[b] + r;
        if (p < CAP) {
            staging[(size_t)b * CAP + p] = (u32)s | ((u32)(d & 255) << 16);
        } else {
            int q = atomicAdd(ovfcur, 1);
            if (q < OVFCAP) ovf[q] = (u32)s | ((u32)d << 16);
        }
    }
}

// Per-bucket counting sort, entirely LDS-cursor based. One block per bucket:
//   hist -> bucket base (reduce gcur) -> local excl scan -> row_start/dinv
//   -> csr fill (LDS cursors) -> scale_x for the bucket's own 256 rows.
// Blocks [nbuck, nbuck+17): weight canonicalization.
// wc layout (u16): [0,8192) W1t[n*64+k] | [8192,16384) W2t[n*128+k]
//                  [16384,16512) b1 | [16512,16576) b2
__global__ __launch_bounds__(256) void k_bucket(
    const u32* __restrict__ staging, const int* __restrict__ gcur,
    const u32* __restrict__ ovf, const int* __restrict__ ovfcur,
    int* __restrict__ row_start, float* __restrict__ dinv,
    u16* __restrict__ csr, int nbuck,
    const void* __restrict__ W1, const void* __restrict__ b1,
    const void* __restrict__ W2, const void* __restrict__ b2,
    u16* __restrict__ wc,
    const void* __restrict__ x, u16* __restrict__ gxt, int N, int E) {
    __shared__ float sflag;
    __shared__ int hcnt[256];
    __shared__ int hscan[256];
    __shared__ int hcur[256];
    __shared__ int sred[256];
    __shared__ int sbase;
    __shared__ float sdinv[256];
    const int bid = blockIdx.x;
    const int tid = threadIdx.x;
    bool isbf = block_isbf((const u16*)x, &sflag);

    if (bid < nbuck) {
        const int b = bid;
        const int used = min(gcur[b], CAP);
        const u32* st = staging + (size_t)b * CAP;
        const int no = min(ovfcur[0], OVFCAP);
        // bucket base = sum gcur[0..b)
        sred[tid] = (tid < b) ? gcur[tid] : 0;
        hcnt[tid] = 0;
        __syncthreads();
        for (int s = 128; s > 0; s >>= 1) {
            if (tid < s) sred[tid] += sred[tid + s];
            __syncthreads();
        }
        if (tid == 0) sbase = sred[0];
        // pass1: per-node hist (staging + overflow)
        for (int i = tid; i < used; i += 256)
            atomicAdd(&hcnt[st[i] >> 16], 1);
        for (int i = tid; i < no; i += 256) {
            u32 pk = ovf[i];
            int d = (int)(pk >> 16);
            if ((d >> BSH) == b) atomicAdd(&hcnt[d & 255], 1);
        }
        __syncthreads();
        // exclusive scan over 256 counts
        int v = hcnt[tid];
        hscan[tid] = v;
        __syncthreads();
        for (int s = 1; s < 256; s <<= 1) {
            int t = (tid >= s) ? hscan[tid - s] : 0;
            __syncthreads();
            hscan[tid] += t;
            __syncthreads();
        }
        int excl = hscan[tid] - v;
        hcur[tid] = excl;
        int base = sbase;
        float dv = rsqrtf((float)(v + 1));
        sdinv[tid] = dv;
        int node = (b << BSH) + tid;
        if (node < N) {
            row_start[node] = base + excl;
            dinv[node] = dv;
        }
        if (b == 0 && tid == 0) row_start[N] = E;
        __syncthreads();
        // pass2: csr fill via LDS cursors (compact 2*CAP-byte csr window)
        for (int i = tid; i < used; i += 256) {
            u32 pk = st[i];
            int r = atomicAdd(&hcur[pk >> 16], 1);
            csr[base + r] = (u16)(pk & 0xFFFFu);
        }
        for (int i = tid; i < no; i += 256) {
            u32 pk = ovf[i];
            int d = (int)(pk >> 16);
            if ((d >> BSH) == b) {
                int r = atomicAdd(&hcur[d & 255], 1);
                csr[base + r] = (u16)(pk & 0xFFFFu);
            }
        }
        // scale_x for our 256 rows: gxt[row] = bf16(x[row] * dinv[row])
        const int row0 = b << BSH;
        for (int i = tid; i < 256 * 16; i += 256) {
            int rl = i >> 4;
            int node2 = row0 + rl;
            if (node2 >= N) break;
            int q = i & 15;
            size_t idx = (size_t)node2 * 16 + q;
            float di = sdinv[rl];
            float4 vv;
            if (isbf) {
                ushort4 u = ((const ushort4*)x)[idx];
                vv.x = bf2f(u.x); vv.y = bf2f(u.y); vv.z = bf2f(u.z); vv.w = bf2f(u.w);
            } else {
                vv = ((const float4*)x)[idx];
            }
            ushort4 o;
            o.x = f2bf(vv.x * di); o.y = f2bf(vv.y * di);
            o.z = f2bf(vv.z * di); o.w = f2bf(vv.w * di);
            ((ushort4*)gxt)[idx] = o;
        }
    } else {
        // weight canonicalize (17 blocks)
        int cb = bid - nbuck;
        for (int i = cb * 256 + tid; i < 16576; i += 17 * 256) {
            const void* s; int off;
            if (i < 8192)       { int nn = i >> 6, k = i & 63;  s = W1; off = k * 128 + nn; }
            else if (i < 16384) { int j = i - 8192; int nn = j >> 7, k = j & 127; s = W2; off = k * 64 + nn; }
            else if (i < 16512) { s = b1; off = i - 16384; }
            else                { s = b2; off = i - 16512; }
            wc[i] = isbf ? ((const u16*)s)[off] : f2bf(((const float*)s)[off]);
        }
    }
}

// gather: out[d] = feat[d] + sum_{j in in(d)} feat[csr[j]]  (32 lanes/node)
template<bool FINAL>
__global__ __launch_bounds__(256) void k_gather(
    const u32* __restrict__ feat, const int* __restrict__ row_start,
    const u16* __restrict__ csr, const float* __restrict__ dinv,
    const u16* __restrict__ b2c, const void* __restrict__ xdet,
    void* __restrict__ outp, int n) {
    __shared__ float sflag;
    bool isbf = true;
    if (FINAL) isbf = block_isbf((const u16*)xdet, &sflag);
    int t = blockIdx.x * 256 + threadIdx.x;
    int d = t >> 5;
    int lane = t & 31;
    if (d >= n) return;
    const u32* fl = feat + lane;
    u32 w = fl[(size_t)d * 32];                 // self-loop
    float ax = bf2f((u16)(w & 0xFFFFu));
    float ay = bf2f((u16)(w >> 16));
    gather_accum(fl, csr, row_start[d], row_start[d + 1], lane, ax, ay);
    if (FINAL) {
        float di = dinv[d];
        ax = ax * di + bf2f(b2c[2 * lane + 0]);
        ay = ay * di + bf2f(b2c[2 * lane + 1]);
        if (isbf) {
            u32 o = (u32)f2bf(ax) | ((u32)f2bf(ay) << 16);
            ((u32*)outp)[(size_t)d * 32 + lane] = o;
        } else {
            ((float2*)outp)[(size_t)d * 32 + lane] = make_float2(ax, ay);
        }
    } else {
        u32 o = (u32)f2bf(ax) | ((u32)f2bf(ay) << 16);
        ((u32*)outp)[(size_t)d * 32 + lane] = o;
    }
}

// MFMA fused 2-layer MLP on a 32-row tile (53 KB LDS -> 3 blocks/CU), in-place safe:
//   h   = relu( bf16(dinv[r]*acc1[r,:]) @ W1 + b1 )   [32 x 128]
//   ht2 = ( h @ W2 ) * dinv[r]                        [32 x 64]  -> bf16 outb
__global__ __launch_bounds__(256) void k_mlp(
    const u16* __restrict__ accin, const u16* __restrict__ wc,
    const float* __restrict__ dinv, u16* outb, int n) {
    __shared__ __align__(16) u16 As[32 * 72];      //  4.5 KB
    __shared__ __align__(16) u16 W1t[128 * 72];    // 18.0 KB
    __shared__ __align__(16) u16 W2t[64 * 136];    // 17.0 KB
    __shared__ __align__(16) u16 Hs[32 * 136];     //  8.5 KB
    __shared__ float b1s[128];
    __shared__ float dvs[32];
    const int tid = threadIdx.x;
    const int row0 = blockIdx.x * 32;

    if (tid < 32) {
        int r = row0 + tid;
        dvs[tid] = (r < n) ? dinv[r] : 0.f;
    } else if (tid < 160) {
        b1s[tid - 32] = bf2f(wc[16384 + tid - 32]);
    }
    for (int i = tid; i < 1024; i += 256) {
        int r = i >> 5, kk = i & 31;
        int row = row0 + r;
        u32 v = 0;
        if (row < n) {
            u32 g = ((const u32*)accin)[(size_t)row * 32 + kk];
            float di = dinv[row];
            u16 lo = f2bf(bf2f((u16)(g & 0xFFFFu)) * di);
            u16 hi = f2bf(bf2f((u16)(g >> 16)) * di);
            v = (u32)lo | ((u32)hi << 16);
        }
        *(u32*)&As[r * 72 + kk * 2] = v;
    }
    for (int i = tid; i < 4096; i += 256) {
        int nn = i >> 5, kk = i & 31;
        *(u32*)&W1t[nn * 72 + kk * 2] = ((const u32*)wc)[i];
    }
    for (int i = tid; i < 4096; i += 256) {
        int nn = i >> 6, kk = i & 63;
        *(u32*)&W2t[nn * 136 + kk * 2] = ((const u32*)wc)[4096 + i];
    }
    __syncthreads();

    const int wave = tid >> 6;     // 0..3
    const int lane = tid & 63;
    const int q = lane >> 4;       // quad
    const int ln = lane & 15;

    // ---- GEMM1: [32x64] @ [64x128] ----
    bf16x8 a[2][2];
#pragma unroll
    for (int mt = 0; mt < 2; mt++)
#pragma unroll
        for (int ks = 0; ks < 2; ks++)
            a[mt][ks] = *(const bf16x8*)&As[(mt * 16 + ln) * 72 + ks * 32 + q * 8];

    f32x4 c1[2][2];   // [ntl][mt]
#pragma unroll
    for (int ntl = 0; ntl < 2; ntl++)
#pragma unroll
        for (int mt = 0; mt < 2; mt++) c1[ntl][mt] = (f32x4){0.f, 0.f, 0.f, 0.f};

#pragma unroll
    for (int ntl = 0; ntl < 2; ntl++) {
        int nt = wave * 2 + ntl;
        bf16x8 b0 = *(const bf16x8*)&W1t[(nt * 16 + ln) * 72 + 0 + q * 8];
        bf16x8 b1f = *(const bf16x8*)&W1t[(nt * 16 + ln) * 72 + 32 + q * 8];
#pragma unroll
        for (int mt = 0; mt < 2; mt++) {
            c1[ntl][mt] = __builtin_amdgcn_mfma_f32_16x16x32_bf16(a[mt][0], b0, c1[ntl][mt], 0, 0, 0);
            c1[ntl][mt] = __builtin_amdgcn_mfma_f32_16x16x32_bf16(a[mt][1], b1f, c1[ntl][mt], 0, 0, 0);
        }
    }
#pragma unroll
    for (int ntl = 0; ntl < 2; ntl++) {
        int col = (wave * 2 + ntl) * 16 + ln;
        float bb = b1s[col];
#pragma unroll
        for (int mt = 0; mt < 2; mt++)
#pragma unroll
            for (int r = 0; r < 4; r++) {
                int hrow = mt * 16 + q * 4 + r;
                Hs[hrow * 136 + col] = f2bf(fmaxf(c1[ntl][mt][r] + bb, 0.f));
            }
    }
    __syncthreads();

    // ---- GEMM2: [32x128] @ [128x64] ----
    f32x4 c2[2];
    c2[0] = (f32x4){0.f, 0.f, 0.f, 0.f};
    c2[1] = (f32x4){0.f, 0.f, 0.f, 0.f};
#pragma unroll
    for (int ks = 0; ks < 4; ks++) {
        bf16x8 bb = *(const bf16x8*)&W2t[(wave * 16 + ln) * 136 + ks * 32 + q * 8];
#pragma unroll
        for (int mt = 0; mt < 2; mt++) {
            bf16x8 aa = *(const bf16x8*)&Hs[(mt * 16 + ln) * 136 + ks * 32 + q * 8];
            c2[mt] = __builtin_amdgcn_mfma_f32_16x16x32_bf16(aa, bb, c2[mt], 0, 0, 0);
        }
    }
#pragma unroll
    for (int mt = 0; mt < 2; mt++)
#pragma unroll
        for (int r = 0; r < 4; r++) {
            int rloc = mt * 16 + q * 4 + r;
            int row = row0 + rloc;
            if (row < n) {
                int col = wave * 16 + ln;
                outb[(size_t)row * 64 + col] = f2bf(c2[mt][r] * dvs[rloc]);
            }
        }
}

extern "C" void kernel_launch(void* const* d_in, const int* in_sizes, int n_in,
                              void* d_out, int out_size, void* d_ws, size_t ws_size,
                              hipStream_t stream) {
    const void* x  = d_in[0];
    const int* ei  = (const int*)d_in[1];
    const void* W1 = d_in[2];
    const void* b1 = d_in[3];
    const void* W2 = d_in[4];
    const void* b2 = d_in[5];

    const int N = in_sizes[0] / 64;   // 50000 (< 65536 required: u16 csr + packing)
    const int E = in_sizes[1] / 2;    // 800000
    const int* src = ei;
    const int* dst = ei + E;

    // workspace (~8.5 MB of d_ws):
    //   dinv[NP] | gcur[256] | ovfcur[+pad 64] | row_start[N+64] | ovf[8192] u32
    //   | csr[E] u16 | wc[16576] u16 | bufB (N*64 u16)
    // staging (nbuck*CAP u32 ~4 MB) aliases bufB (dead until k_mlp writes it).
    // xt lives in d_out (scratch until k_gather<true> rewrites it).
    float* ws = (float*)d_ws;
    const int NP = ((N + 64) + 63) & ~63;
    float* dinv    = ws;
    int* gcur      = (int*)(ws + NP);
    int* ovfcur    = gcur + 256;
    int* row_start = gcur + 320;
    u32* ovf       = (u32*)(row_start + ((N + 64) & ~63));
    u16* csr       = (u16*)(ovf + OVFCAP);
    u16* wc        = (u16*)(((size_t)(csr + E) + 255) & ~(size_t)255);
    u16* bufB      = (u16*)(((size_t)(wc + 16576) + 255) & ~(size_t)255);
    u32* staging   = (u32*)bufB;
    u16* gxt       = (u16*)d_out;

    const int gth = (N * 32 + 255) / 256;      // gather grid
    const int nbuck = (N + 255) >> BSH;        // 196 (<=256 required)
    const int binB = (E + CHUNK - 1) / CHUNK;  // 391
    dim3 blk(256);

    // zero gcur + ovfcur (graph-capture legal)
    hipMemsetAsync(gcur, 0, 320 * sizeof(int), stream);
    // bin edges into per-bucket staging (no per-node atomics)
    k_binA2<<<dim3(binB), blk, 0, stream>>>(src, dst, gcur, staging, ovf, ovfcur, E);
    // per-bucket counting sort (row_start/dinv/csr) + scale_x + weight canon
    k_bucket<<<dim3(nbuck + 17), blk, 0, stream>>>(staging, gcur, ovf, ovfcur,
                                                   row_start, dinv, csr, nbuck,
                                                   W1, b1, W2, b2, wc, x, gxt, N, E);
    // acc1 = gather(xt) -> bufB (staging now dead)
    k_gather<false><<<dim3(gth), blk, 0, stream>>>((const u32*)gxt, row_start, csr,
                                                   dinv, wc + 16512, x, bufB, N);
    // ht2 = (relu(dinv*acc1 @ W1 + b1) @ W2)*dinv -> bufB (in-place, row-local)
    k_mlp<<<dim3((N + 31) / 32), blk, 0, stream>>>((const u16*)bufB, wc, dinv, bufB, N);
    // out = bf16( (ht2[d]+gather(ht2))*dinv + b2 ) -> d_out
    k_gather<true><<<dim3(gth), blk, 0, stream>>>((const u32*)bufB, row_start, csr,
                                                  dinv, wc + 16512, x, d_out, N);
}